// Round 4
// baseline (178.542 us; speedup 1.0000x reference)
//
#include <hip/hip_runtime.h>
#include <math.h>

#define HW    9216
#define KJ    17
#define BATCH 128
#define TOPK  8

// Kernel 1: per-(b,k) sum of squared diff. One block per row (b*17+k).
// 256 threads x 9 float4 per input, fully coalesced.
//
// R2 post-mortem: sched_barrier alone left VGPR=40 (can't hold 18 float4) —
// the register allocator was capped by the default max-occupancy target, so
// loads stayed serialized (issue->drain->fma, 60us, VALUBusy 3%).
// Fix: __launch_bounds__(256, 2) lifts the VGPR budget to ~256/wave, and 18
// NAMED float4 locals (straight-line, no arrays) make each load an
// independent SSA value. 8 waves/CU x 18 x 64 x 16B = 147KB in flight/CU.
__global__ __launch_bounds__(256, 2) void per_joint_mse(
    const float* __restrict__ outp, const float* __restrict__ tgt,
    const float* __restrict__ tw, float* __restrict__ pj)
{
    const int row = blockIdx.x;            // b*KJ + k
    const float4* o4 = (const float4*)(outp + (size_t)row * HW);
    const float4* t4 = (const float4*)(tgt  + (size_t)row * HW);
    const int tid = threadIdx.x;

    float4 o0 = o4[tid + 0 * 256];  float4 t0 = t4[tid + 0 * 256];
    float4 o1 = o4[tid + 1 * 256];  float4 t1 = t4[tid + 1 * 256];
    float4 o2 = o4[tid + 2 * 256];  float4 t2 = t4[tid + 2 * 256];
    float4 o3 = o4[tid + 3 * 256];  float4 t3 = t4[tid + 3 * 256];
    float4 o4v = o4[tid + 4 * 256]; float4 t4v = t4[tid + 4 * 256];
    float4 o5 = o4[tid + 5 * 256];  float4 t5 = t4[tid + 5 * 256];
    float4 o6 = o4[tid + 6 * 256];  float4 t6 = t4[tid + 6 * 256];
    float4 o7 = o4[tid + 7 * 256];  float4 t7 = t4[tid + 7 * 256];
    float4 o8 = o4[tid + 8 * 256];  float4 t8 = t4[tid + 8 * 256];

    // Nothing crosses this: all 18 loads issued before any compute.
    __builtin_amdgcn_sched_barrier(0);

    float acc = 0.f;
#define ACCUM(o, t)                                                  \
    {                                                                \
        float d0 = o.x - t.x, d1 = o.y - t.y;                        \
        float d2 = o.z - t.z, d3 = o.w - t.w;                        \
        acc += d0 * d0 + d1 * d1 + d2 * d2 + d3 * d3;                \
    }
    ACCUM(o0, t0) ACCUM(o1, t1) ACCUM(o2, t2) ACCUM(o3, t3)
    ACCUM(o4v, t4v) ACCUM(o5, t5) ACCUM(o6, t6) ACCUM(o7, t7)
    ACCUM(o8, t8)
#undef ACCUM

    // wave64 shuffle reduce
#pragma unroll
    for (int off = 32; off > 0; off >>= 1)
        acc += __shfl_down(acc, off, 64);

    __shared__ float smem[4];
    const int wave = tid >> 6;
    if ((tid & 63) == 0) smem[wave] = acc;
    __syncthreads();
    if (tid == 0) {
        const float w = tw[row];
        float tot = smem[0] + smem[1] + smem[2] + smem[3];
        pj[row] = tot * w * w * (1.0f / (float)HW);
    }
}

// Kernel 2: per-sample top-8-of-17, then mean over batch. 1 block, 128 threads.
__global__ __launch_bounds__(128) void ohkm_reduce(
    const float* __restrict__ pj, float* __restrict__ result)
{
    const int b = threadIdx.x;   // 0..127 — one sample per thread
    float v[KJ];
#pragma unroll
    for (int k = 0; k < KJ; ++k) v[k] = pj[b * KJ + k];

    float s = 0.f;
#pragma unroll
    for (int t = 0; t < TOPK; ++t) {
        float m = v[0];
#pragma unroll
        for (int k = 1; k < KJ; ++k) m = fmaxf(m, v[k]);
        s += m;
        // remove exactly the FIRST element equal to m (tie-safe top_k semantics)
        bool removed = false;
#pragma unroll
        for (int k = 0; k < KJ; ++k) {
            bool hit = (!removed) && (v[k] == m);
            v[k] = hit ? -INFINITY : v[k];
            removed = removed || hit;
        }
    }

    // 128 threads = 2 waves
#pragma unroll
    for (int off = 32; off > 0; off >>= 1)
        s += __shfl_down(s, off, 64);

    __shared__ float smem[2];
    if ((b & 63) == 0) smem[b >> 6] = s;
    __syncthreads();
    if (b == 0)
        result[0] = (smem[0] + smem[1]) * (1.0f / (float)(BATCH * TOPK));
}

extern "C" void kernel_launch(void* const* d_in, const int* in_sizes, int n_in,
                              void* d_out, int out_size, void* d_ws, size_t ws_size,
                              hipStream_t stream) {
    const float* outp = (const float*)d_in[0];   // [128,17,96,96]
    const float* tgt  = (const float*)d_in[1];   // [128,17,96,96]
    const float* tw   = (const float*)d_in[2];   // [128,17,1]
    float* result = (float*)d_out;               // scalar
    float* pj = (float*)d_ws;                    // [128*17] per-joint MSE

    per_joint_mse<<<BATCH * KJ, 256, 0, stream>>>(outp, tgt, tw, pj);
    ohkm_reduce<<<1, 128, 0, stream>>>(pj, result);
}

// Round 5
// 178.191 us; speedup vs baseline: 1.0020x; 1.0020x over previous
//
#include <hip/hip_runtime.h>
#include <math.h>

#define HW    9216
#define KJ    17
#define BATCH 128
#define TOPK  8
#define ROWS  (BATCH * KJ)          // 2176
#define F4_PER_ROW (HW / 4)         // 2304
#define BLOCKS_PER_ROW (F4_PER_ROW / 256)  // 9

// R3 post-mortem: kernel time was invariant to cache state (warm replay w/
// FETCH~0 still 60us) -> latency-chain bound, not BW bound. 235 cy/wave-load
// = L2-hit latency; each wave ran a 9-deep load->vmcnt(0)->fma chain and the
// RA refused >40 VGPR at source level. Fix: chain length 1 — one float4 pair
// per THREAD, 9 blocks per row, atomicAdd partial sums. Max occupancy keeps
// the CU issuing fresh first-loads every cycle.
__global__ __launch_bounds__(256) void sq_partial(
    const float* __restrict__ outp, const float* __restrict__ tgt,
    float* __restrict__ pj_sum)
{
    const int tid = threadIdx.x;
    const int idx = blockIdx.x * 256 + tid;          // flat float4 index
    const int row = blockIdx.x / BLOCKS_PER_ROW;     // 2304 f4/row = 9 blocks

    float4 ov = ((const float4*)outp)[idx];
    float4 tv = ((const float4*)tgt)[idx];
    float d0 = ov.x - tv.x;
    float d1 = ov.y - tv.y;
    float d2 = ov.z - tv.z;
    float d3 = ov.w - tv.w;
    float ss = d0 * d0 + d1 * d1 + d2 * d2 + d3 * d3;

    // wave64 shuffle reduce
#pragma unroll
    for (int off = 32; off > 0; off >>= 1)
        ss += __shfl_down(ss, off, 64);

    __shared__ float smem[4];
    if ((tid & 63) == 0) smem[tid >> 6] = ss;
    __syncthreads();
    if (tid == 0)
        atomicAdd(&pj_sum[row], smem[0] + smem[1] + smem[2] + smem[3]);
}

// Kernel 2: scale by w^2/HW, per-sample top-8-of-17, mean over batch.
__global__ __launch_bounds__(128) void ohkm_reduce(
    const float* __restrict__ pj_sum, const float* __restrict__ tw,
    float* __restrict__ result)
{
    const int b = threadIdx.x;   // 0..127 — one sample per thread
    float v[KJ];
#pragma unroll
    for (int k = 0; k < KJ; ++k) {
        float w = tw[b * KJ + k];
        v[k] = pj_sum[b * KJ + k] * w * w * (1.0f / (float)HW);
    }

    float s = 0.f;
#pragma unroll
    for (int t = 0; t < TOPK; ++t) {
        float m = v[0];
#pragma unroll
        for (int k = 1; k < KJ; ++k) m = fmaxf(m, v[k]);
        s += m;
        // remove exactly the FIRST element equal to m (tie-safe top_k)
        bool removed = false;
#pragma unroll
        for (int k = 0; k < KJ; ++k) {
            bool hit = (!removed) && (v[k] == m);
            v[k] = hit ? -INFINITY : v[k];
            removed = removed || hit;
        }
    }

    // 128 threads = 2 waves
#pragma unroll
    for (int off = 32; off > 0; off >>= 1)
        s += __shfl_down(s, off, 64);

    __shared__ float smem[2];
    if ((b & 63) == 0) smem[b >> 6] = s;
    __syncthreads();
    if (b == 0)
        result[0] = (smem[0] + smem[1]) * (1.0f / (float)(BATCH * TOPK));
}

extern "C" void kernel_launch(void* const* d_in, const int* in_sizes, int n_in,
                              void* d_out, int out_size, void* d_ws, size_t ws_size,
                              hipStream_t stream) {
    const float* outp = (const float*)d_in[0];   // [128,17,96,96]
    const float* tgt  = (const float*)d_in[1];   // [128,17,96,96]
    const float* tw   = (const float*)d_in[2];   // [128,17,1]
    float* result = (float*)d_out;               // scalar
    float* pj_sum = (float*)d_ws;                // [2176] unweighted sum(d^2)

    // d_ws is poisoned 0xAA before every launch — zero the accumulators.
    hipMemsetAsync(pj_sum, 0, ROWS * sizeof(float), stream);
    sq_partial<<<ROWS * BLOCKS_PER_ROW, 256, 0, stream>>>(outp, tgt, pj_sum);
    ohkm_reduce<<<1, 128, 0, stream>>>(pj_sum, tw, result);
}